// Round 3
// baseline (5274.334 us; speedup 1.0000x reference)
//
#include <hip/hip_runtime.h>
#include <math.h>

#define D_MODEL 1024
#define D4      256     // float4s per token
#define SLEN    2048
#define BATCH   2
#define NTOK    4096
#define NLAYER  8
#define V1N     200
#define V2N     160
#define CHUNK   32
#define NCH     64      // CHUNK*NCH == SLEN
#define EPSF    1e-6f

__device__ __forceinline__ float block_reduce_sum(float v, float* sred) {
    // 256 threads = 4 waves of 64
    #pragma unroll
    for (int off = 32; off > 0; off >>= 1) v += __shfl_down(v, off, 64);
    int lane = threadIdx.x & 63, w = threadIdx.x >> 6;
    if (lane == 0) sred[w] = v;
    __syncthreads();
    float s = sred[0] + sred[1] + sred[2] + sred[3];
    __syncthreads();  // safe reuse of sred
    return s;
}

__device__ __forceinline__ float geluf(float x) {
    float x3 = x * x * x;
    return 0.5f * x * (1.0f + tanhf(0.7978845608028654f * (x + 0.044715f * x3)));
}

// ---- precompute sigmoid(lam) and its CHUNK-th power --------------------------
__global__ void precompute_kernel(const float* __restrict__ lam,
                                  float* __restrict__ decay,
                                  float* __restrict__ apow) {
    int i = blockIdx.x * 256 + threadIdx.x;   // NLAYER*D_MODEL = 8192
    float a = 1.0f / (1.0f + expf(-lam[i]));
    decay[i] = a;
    float p = a;
    p = p * p; p = p * p; p = p * p; p = p * p; p = p * p;  // a^32
    apow[i] = p;
}

// ---- TT embedding + layer-0 rstd --------------------------------------------
__global__ void embed_kernel(const int* __restrict__ ids,
                             const float* __restrict__ c1,
                             const float* __restrict__ c2,
                             float* __restrict__ xbuf,
                             float* __restrict__ rstd) {
    __shared__ float sred[4];
    int tok = blockIdx.x, t = threadIdx.x;
    int id = ids[tok];
    int i1 = id / V2N, i2 = id % V2N;
    int i = t >> 3, j0 = (t & 7) * 4;
    float a = c1[i1 * 32 + i];
    float4 b = *(const float4*)(c2 + i2 * 32 + j0);
    float4 e; e.x = a * b.x; e.y = a * b.y; e.z = a * b.z; e.w = a * b.w;
    ((float4*)xbuf)[(size_t)tok * D4 + t] = e;
    float ss = e.x * e.x + e.y * e.y + e.z * e.z + e.w * e.w;
    ss = block_reduce_sum(ss, sred);
    if (t == 0) rstd[tok] = rsqrtf(ss * (1.0f / D_MODEL) + EPSF);
}

// ---- scan pass 1: local chunk scans (h0 = 0) -> carries ----------------------
__global__ void scan1_kernel(const float* __restrict__ xbuf,
                             const float* __restrict__ rstd,
                             const float* __restrict__ decay,
                             const float* __restrict__ vw,
                             const float* __restrict__ n1w,
                             float* __restrict__ carry, int l) {
    __shared__ float srs[CHUNK];
    int bid = blockIdx.x;
    int cg = bid & 3, k = (bid >> 2) & 63, b = bid >> 8;
    int c = cg * 256 + threadIdx.x;
    int s0 = k * CHUNK;
    if (threadIdx.x < CHUNK) srs[threadIdx.x] = rstd[b * SLEN + s0 + threadIdx.x];
    __syncthreads();
    float a  = decay[l * D_MODEL + c];
    float vv = vw[l * D_MODEL + c];
    float n1 = n1w[l * D_MODEL + c];
    const float* xp = xbuf + (size_t)(b * SLEN + s0) * D_MODEL + c;
    float h = 0.0f;
    #pragma unroll
    for (int si = 0; si < CHUNK; ++si) {
        float xn = xp[si * D_MODEL] * srs[si] * n1;
        h = a * h + vv * xn;
    }
    carry[(size_t)(b * NCH + k) * D_MODEL + c] = h;
}

// ---- scan pass 2: per-channel prefix over chunk carries ----------------------
__global__ void scan2_kernel(const float* __restrict__ carry,
                             const float* __restrict__ apow,
                             float* __restrict__ hstart, int l) {
    int gid = blockIdx.x * 256 + threadIdx.x;  // BATCH*D_MODEL = 2048
    int b = gid >> 10, c = gid & 1023;
    float A = apow[l * D_MODEL + c];
    float H = 0.0f;
    #pragma unroll 8
    for (int k = 0; k < NCH; ++k) {
        size_t idx = (size_t)(b * NCH + k) * D_MODEL + c;
        hstart[idx] = H;
        H = A * H + carry[idx];
    }
}

// ---- scan pass 3: apply with correct h0, x += u*h ----------------------------
__global__ void scan3_kernel(float* __restrict__ xbuf,
                             const float* __restrict__ rstd,
                             const float* __restrict__ hstart,
                             const float* __restrict__ decay,
                             const float* __restrict__ vw,
                             const float* __restrict__ uw,
                             const float* __restrict__ n1w, int l) {
    __shared__ float srs[CHUNK];
    int bid = blockIdx.x;
    int cg = bid & 3, k = (bid >> 2) & 63, b = bid >> 8;
    int c = cg * 256 + threadIdx.x;
    int s0 = k * CHUNK;
    if (threadIdx.x < CHUNK) srs[threadIdx.x] = rstd[b * SLEN + s0 + threadIdx.x];
    __syncthreads();
    float a  = decay[l * D_MODEL + c];
    float vv = vw[l * D_MODEL + c];
    float uu = uw[l * D_MODEL + c];
    float n1 = n1w[l * D_MODEL + c];
    float h = hstart[(size_t)(b * NCH + k) * D_MODEL + c];
    float* xp = xbuf + (size_t)(b * SLEN + s0) * D_MODEL + c;
    #pragma unroll
    for (int si = 0; si < CHUNK; ++si) {
        float xv = xp[si * D_MODEL];
        float xn = xv * srs[si] * n1;
        h = a * h + vv * xn;
        xp[si * D_MODEL] = xv + uu * h;
    }
}

// ---- rank-2 FFN + residual + next-layer rstd --------------------------------
__global__ void ffn_kernel(float* __restrict__ xbuf,
                           float* __restrict__ rstd,
                           const float* __restrict__ n2w,
                           const float* __restrict__ w1,
                           const float* __restrict__ w2, int l) {
    __shared__ float sred[4];
    __shared__ float sred2[8];
    int tok = blockIdx.x, t = threadIdx.x;
    float4 xv = ((float4*)xbuf)[(size_t)tok * D4 + t];
    float ss = xv.x * xv.x + xv.y * xv.y + xv.z * xv.z + xv.w * xv.w;
    ss = block_reduce_sum(ss, sred);
    float rs2 = rsqrtf(ss * (1.0f / D_MODEL) + EPSF);
    float4 n2 = ((const float4*)(n2w + (size_t)l * D_MODEL))[t];
    float4 h;
    h.x = xv.x * rs2 * n2.x; h.y = xv.y * rs2 * n2.y;
    h.z = xv.z * rs2 * n2.z; h.w = xv.w * rs2 * n2.w;
    const float4* w1p = (const float4*)(w1 + (size_t)l * D_MODEL * 2);
    float4 w1a = w1p[t * 2], w1b = w1p[t * 2 + 1];
    // w1 layout [c][r]: w1a = (c0r0,c0r1,c1r0,c1r1), w1b = (c2r0,c2r1,c3r0,c3r1)
    float t0 = h.x * w1a.x + h.y * w1a.z + h.z * w1b.x + h.w * w1b.z;
    float t1 = h.x * w1a.y + h.y * w1a.w + h.z * w1b.y + h.w * w1b.w;
    #pragma unroll
    for (int off = 32; off > 0; off >>= 1) {
        t0 += __shfl_down(t0, off, 64);
        t1 += __shfl_down(t1, off, 64);
    }
    int lane = t & 63, w = t >> 6;
    if (lane == 0) { sred2[w * 2] = t0; sred2[w * 2 + 1] = t1; }
    __syncthreads();
    t0 = sred2[0] + sred2[2] + sred2[4] + sred2[6];
    t1 = sred2[1] + sred2[3] + sred2[5] + sred2[7];
    float g0 = geluf(t0), g1 = geluf(t1);
    float4 w20 = ((const float4*)(w2 + (size_t)(l * 2 + 0) * D_MODEL))[t];
    float4 w21 = ((const float4*)(w2 + (size_t)(l * 2 + 1) * D_MODEL))[t];
    xv.x += g0 * w20.x + g1 * w21.x;
    xv.y += g0 * w20.y + g1 * w21.y;
    xv.z += g0 * w20.z + g1 * w21.z;
    xv.w += g0 * w20.w + g1 * w21.w;
    ((float4*)xbuf)[(size_t)tok * D4 + t] = xv;
    float ss2 = xv.x * xv.x + xv.y * xv.y + xv.z * xv.z + xv.w * xv.w;
    ss2 = block_reduce_sum(ss2, sred);
    if (t == 0) rstd[tok] = rsqrtf(ss2 * (1.0f / D_MODEL) + EPSF);
}

// ---- final rmsnorm + factorized tied-projection logits -----------------------
// logits[t, v1*160+v2] = sum_i c1[v1,i] * T[v2,i],  T[v2,i] = sum_j Xn[i,j]*c2[v2,j]
// 512 threads/block; phase C gives each thread exactly ONE 8x8 output tile
// (500 active) so the 64 accumulators trivially fit in registers -- the
// previous 2x-unrolled tile loop interleaved two tile bodies and spilled the
// accumulators to scratch (11+ GB of phantom HBM traffic per dispatch).
// c1 (25.6 KB) is NOT staged in LDS: it is L1-resident and read broadcast-style
// (20 lanes share each row), moving Ar loads onto the idle VMEM pipe.
// Phase C lane mapping: tv2 varies FASTEST across lanes -> a wave's stores
// cover contiguous output rows (coalesced full-line writes, no RMW fetch).
// sT is xor-swizzled by (v2>>3) so tv2-spread lanes hit distinct bank groups.
__global__ __launch_bounds__(512, 4) void logits_kernel(
        const float* __restrict__ xbuf,
        const float* __restrict__ rstd,
        const float* __restrict__ fnw,
        const float* __restrict__ c1,
        const float* __restrict__ c2,
        float* __restrict__ out) {
    __shared__ float sX[1024];    // swizzled float4 rows: slot i*8 + (j4 ^ (i&7))
    __shared__ float sT[5120];    // swizzled: slot v2*8 + (i4 ^ ((v2>>3)&7))
    int tok = blockIdx.x, t = threadIdx.x;

    // phase A: final rmsnorm into LDS (first 256 threads; one float4 each)
    if (t < 256) {
        float rs = rstd[tok];
        float4 xv = ((const float4*)xbuf)[(size_t)tok * D4 + t];
        float4 fn = ((const float4*)fnw)[t];
        float4 xs;
        xs.x = xv.x * rs * fn.x; xs.y = xv.y * rs * fn.y;
        xs.z = xv.z * rs * fn.z; xs.w = xv.w * rs * fn.w;
        int i = t >> 3, j4 = t & 7;
        ((float4*)sX)[i * 8 + (j4 ^ (i & 7))] = xs;
    }
    __syncthreads();

    // phase B: T[v2][i]; each thread owns one i-row (in regs) x 10 v2
    {
        int i = t & 31;
        int vg = t >> 5;  // 0..15
        float4 xr[8];
        #pragma unroll
        for (int j4 = 0; j4 < 8; ++j4)
            xr[j4] = ((const float4*)sX)[i * 8 + (j4 ^ (i & 7))];
        #pragma unroll
        for (int o = 0; o < 10; ++o) {
            int v2 = vg * 10 + o;
            const float4* c2p = (const float4*)(c2 + v2 * 32);
            float acc = 0.0f;
            #pragma unroll
            for (int j4 = 0; j4 < 8; ++j4) {
                float4 cb = c2p[j4];
                acc += cb.x * xr[j4].x + cb.y * xr[j4].y +
                       cb.z * xr[j4].z + cb.w * xr[j4].w;
            }
            int swzB = (v2 >> 3) & 7;
            sT[(v2 * 8 + ((i >> 2) ^ swzB)) * 4 + (i & 3)] = acc;
        }
    }
    __syncthreads();

    // phase C: one 8x8 register tile per thread over the 200x160 output,
    // tv2 lane-fastest for coalesced stores
    if (t < 500) {
        int tv2 = t % 20, tv1 = t / 20;  // lanes vary tv2 fastest
        int v1b = tv1 * 8, v2b = tv2 * 8;
        int swzB = tv2 & 7;
        float acc[8][8];
        #pragma unroll
        for (int r = 0; r < 8; ++r)
            #pragma unroll
            for (int cc = 0; cc < 8; ++cc) acc[r][cc] = 0.0f;
        const float4* c1p = (const float4*)c1;  // c1[v1] = 8 float4s
        #pragma unroll
        for (int i4 = 0; i4 < 8; ++i4) {
            float4 Bc[8];
            #pragma unroll
            for (int cc = 0; cc < 8; ++cc)
                Bc[cc] = ((const float4*)sT)[(v2b + cc) * 8 + (i4 ^ swzB)];
            #pragma unroll
            for (int r = 0; r < 8; ++r) {
                float4 Ar = c1p[(v1b + r) * 8 + i4];   // L1-hit broadcast load
                #pragma unroll
                for (int cc = 0; cc < 8; ++cc)
                    acc[r][cc] += Ar.x * Bc[cc].x + Ar.y * Bc[cc].y +
                                  Ar.z * Bc[cc].z + Ar.w * Bc[cc].w;
            }
        }
        size_t obase = (size_t)tok * 32000;
        #pragma unroll
        for (int r = 0; r < 8; ++r) {
            float4 o0 = {acc[r][0], acc[r][1], acc[r][2], acc[r][3]};
            float4 o1 = {acc[r][4], acc[r][5], acc[r][6], acc[r][7]};
            float* op = out + obase + (size_t)(v1b + r) * 160 + v2b;
            *(float4*)op = o0;
            *(float4*)(op + 4) = o1;
        }
    }
}

extern "C" void kernel_launch(void* const* d_in, const int* in_sizes, int n_in,
                              void* d_out, int out_size, void* d_ws, size_t ws_size,
                              hipStream_t stream) {
    const int*   ids = (const int*)d_in[0];
    const float* c1  = (const float*)d_in[1];
    const float* c2  = (const float*)d_in[2];
    const float* lam = (const float*)d_in[3];
    const float* u   = (const float*)d_in[4];
    const float* v   = (const float*)d_in[5];
    const float* w1  = (const float*)d_in[6];
    const float* w2  = (const float*)d_in[7];
    const float* n1w = (const float*)d_in[8];
    const float* n2w = (const float*)d_in[9];
    const float* fnw = (const float*)d_in[10];
    float* out = (float*)d_out;

    float* ws     = (float*)d_ws;
    float* xbuf   = ws;                                   // 4096*1024
    float* rstd   = xbuf + (size_t)NTOK * D_MODEL;        // 4096
    float* decay  = rstd + NTOK;                          // 8192
    float* apow   = decay + NLAYER * D_MODEL;             // 8192
    float* carry  = apow + NLAYER * D_MODEL;              // 2*64*1024
    float* hstart = carry + (size_t)BATCH * NCH * D_MODEL;// 2*64*1024

    precompute_kernel<<<32, 256, 0, stream>>>(lam, decay, apow);
    embed_kernel<<<NTOK, 256, 0, stream>>>(ids, c1, c2, xbuf, rstd);
    for (int l = 0; l < NLAYER; ++l) {
        scan1_kernel<<<BATCH * NCH * 4, 256, 0, stream>>>(xbuf, rstd, decay, v, n1w, carry, l);
        scan2_kernel<<<BATCH * D_MODEL / 256, 256, 0, stream>>>(carry, apow, hstart, l);
        scan3_kernel<<<BATCH * NCH * 4, 256, 0, stream>>>(xbuf, rstd, hstart, decay, v, u, n1w, l);
        ffn_kernel<<<NTOK, 256, 0, stream>>>(xbuf, rstd, n2w, w1, w2, l);
    }
    logits_kernel<<<NTOK, 512, 0, stream>>>(xbuf, rstd, fnw, c1, c2, out);
}

// Round 5
// 2601.706 us; speedup vs baseline: 2.0273x; 2.0273x over previous
//
#include <hip/hip_runtime.h>
#include <math.h>

#define D_MODEL 1024
#define D4      256     // float4s per token
#define SLEN    2048
#define BATCH   2
#define NTOK    4096
#define NLAYER  8
#define V1N     200
#define V2N     160
#define CHUNK   32
#define NCH     64      // CHUNK*NCH == SLEN
#define EPSF    1e-6f

__device__ __forceinline__ float block_reduce_sum(float v, float* sred) {
    // 256 threads = 4 waves of 64
    #pragma unroll
    for (int off = 32; off > 0; off >>= 1) v += __shfl_down(v, off, 64);
    int lane = threadIdx.x & 63, w = threadIdx.x >> 6;
    if (lane == 0) sred[w] = v;
    __syncthreads();
    float s = sred[0] + sred[1] + sred[2] + sred[3];
    __syncthreads();  // safe reuse of sred
    return s;
}

__device__ __forceinline__ float geluf(float x) {
    float x3 = x * x * x;
    return 0.5f * x * (1.0f + tanhf(0.7978845608028654f * (x + 0.044715f * x3)));
}

// ---- precompute sigmoid(lam) and its CHUNK-th power --------------------------
__global__ void precompute_kernel(const float* __restrict__ lam,
                                  float* __restrict__ decay,
                                  float* __restrict__ apow) {
    int i = blockIdx.x * 256 + threadIdx.x;   // NLAYER*D_MODEL = 8192
    float a = 1.0f / (1.0f + expf(-lam[i]));
    decay[i] = a;
    float p = a;
    p = p * p; p = p * p; p = p * p; p = p * p; p = p * p;  // a^32
    apow[i] = p;
}

// ---- TT embedding + layer-0 rstd --------------------------------------------
__global__ void embed_kernel(const int* __restrict__ ids,
                             const float* __restrict__ c1,
                             const float* __restrict__ c2,
                             float* __restrict__ xbuf,
                             float* __restrict__ rstd) {
    __shared__ float sred[4];
    int tok = blockIdx.x, t = threadIdx.x;
    int id = ids[tok];
    int i1 = id / V2N, i2 = id % V2N;
    int i = t >> 3, j0 = (t & 7) * 4;
    float a = c1[i1 * 32 + i];
    float4 b = *(const float4*)(c2 + i2 * 32 + j0);
    float4 e; e.x = a * b.x; e.y = a * b.y; e.z = a * b.z; e.w = a * b.w;
    ((float4*)xbuf)[(size_t)tok * D4 + t] = e;
    float ss = e.x * e.x + e.y * e.y + e.z * e.z + e.w * e.w;
    ss = block_reduce_sum(ss, sred);
    if (t == 0) rstd[tok] = rsqrtf(ss * (1.0f / D_MODEL) + EPSF);
}

// ---- scan pass 1: local chunk scans (h0 = 0) -> carries ----------------------
__global__ void scan1_kernel(const float* __restrict__ xbuf,
                             const float* __restrict__ rstd,
                             const float* __restrict__ decay,
                             const float* __restrict__ vw,
                             const float* __restrict__ n1w,
                             float* __restrict__ carry, int l) {
    __shared__ float srs[CHUNK];
    int bid = blockIdx.x;
    int cg = bid & 3, k = (bid >> 2) & 63, b = bid >> 8;
    int c = cg * 256 + threadIdx.x;
    int s0 = k * CHUNK;
    if (threadIdx.x < CHUNK) srs[threadIdx.x] = rstd[b * SLEN + s0 + threadIdx.x];
    __syncthreads();
    float a  = decay[l * D_MODEL + c];
    float vv = vw[l * D_MODEL + c];
    float n1 = n1w[l * D_MODEL + c];
    const float* xp = xbuf + (size_t)(b * SLEN + s0) * D_MODEL + c;
    float h = 0.0f;
    #pragma unroll
    for (int si = 0; si < CHUNK; ++si) {
        float xn = xp[si * D_MODEL] * srs[si] * n1;
        h = a * h + vv * xn;
    }
    carry[(size_t)(b * NCH + k) * D_MODEL + c] = h;
}

// ---- scan pass 2: per-channel prefix over chunk carries ----------------------
__global__ void scan2_kernel(const float* __restrict__ carry,
                             const float* __restrict__ apow,
                             float* __restrict__ hstart, int l) {
    int gid = blockIdx.x * 256 + threadIdx.x;  // BATCH*D_MODEL = 2048
    int b = gid >> 10, c = gid & 1023;
    float A = apow[l * D_MODEL + c];
    float H = 0.0f;
    #pragma unroll 8
    for (int k = 0; k < NCH; ++k) {
        size_t idx = (size_t)(b * NCH + k) * D_MODEL + c;
        hstart[idx] = H;
        H = A * H + carry[idx];
    }
}

// ---- scan pass 3: apply with correct h0, x += u*h ----------------------------
__global__ void scan3_kernel(float* __restrict__ xbuf,
                             const float* __restrict__ rstd,
                             const float* __restrict__ hstart,
                             const float* __restrict__ decay,
                             const float* __restrict__ vw,
                             const float* __restrict__ uw,
                             const float* __restrict__ n1w, int l) {
    __shared__ float srs[CHUNK];
    int bid = blockIdx.x;
    int cg = bid & 3, k = (bid >> 2) & 63, b = bid >> 8;
    int c = cg * 256 + threadIdx.x;
    int s0 = k * CHUNK;
    if (threadIdx.x < CHUNK) srs[threadIdx.x] = rstd[b * SLEN + s0 + threadIdx.x];
    __syncthreads();
    float a  = decay[l * D_MODEL + c];
    float vv = vw[l * D_MODEL + c];
    float uu = uw[l * D_MODEL + c];
    float n1 = n1w[l * D_MODEL + c];
    float h = hstart[(size_t)(b * NCH + k) * D_MODEL + c];
    float* xp = xbuf + (size_t)(b * SLEN + s0) * D_MODEL + c;
    #pragma unroll
    for (int si = 0; si < CHUNK; ++si) {
        float xv = xp[si * D_MODEL];
        float xn = xv * srs[si] * n1;
        h = a * h + vv * xn;
        xp[si * D_MODEL] = xv + uu * h;
    }
}

// ---- rank-2 FFN + residual + next-layer rstd --------------------------------
__global__ void ffn_kernel(float* __restrict__ xbuf,
                           float* __restrict__ rstd,
                           const float* __restrict__ n2w,
                           const float* __restrict__ w1,
                           const float* __restrict__ w2, int l) {
    __shared__ float sred[4];
    __shared__ float sred2[8];
    int tok = blockIdx.x, t = threadIdx.x;
    float4 xv = ((float4*)xbuf)[(size_t)tok * D4 + t];
    float ss = xv.x * xv.x + xv.y * xv.y + xv.z * xv.z + xv.w * xv.w;
    ss = block_reduce_sum(ss, sred);
    float rs2 = rsqrtf(ss * (1.0f / D_MODEL) + EPSF);
    float4 n2 = ((const float4*)(n2w + (size_t)l * D_MODEL))[t];
    float4 h;
    h.x = xv.x * rs2 * n2.x; h.y = xv.y * rs2 * n2.y;
    h.z = xv.z * rs2 * n2.z; h.w = xv.w * rs2 * n2.w;
    const float4* w1p = (const float4*)(w1 + (size_t)l * D_MODEL * 2);
    float4 w1a = w1p[t * 2], w1b = w1p[t * 2 + 1];
    // w1 layout [c][r]: w1a = (c0r0,c0r1,c1r0,c1r1), w1b = (c2r0,c2r1,c3r0,c3r1)
    float t0 = h.x * w1a.x + h.y * w1a.z + h.z * w1b.x + h.w * w1b.z;
    float t1 = h.x * w1a.y + h.y * w1a.w + h.z * w1b.y + h.w * w1b.w;
    #pragma unroll
    for (int off = 32; off > 0; off >>= 1) {
        t0 += __shfl_down(t0, off, 64);
        t1 += __shfl_down(t1, off, 64);
    }
    int lane = t & 63, w = t >> 6;
    if (lane == 0) { sred2[w * 2] = t0; sred2[w * 2 + 1] = t1; }
    __syncthreads();
    t0 = sred2[0] + sred2[2] + sred2[4] + sred2[6];
    t1 = sred2[1] + sred2[3] + sred2[5] + sred2[7];
    float g0 = geluf(t0), g1 = geluf(t1);
    float4 w20 = ((const float4*)(w2 + (size_t)(l * 2 + 0) * D_MODEL))[t];
    float4 w21 = ((const float4*)(w2 + (size_t)(l * 2 + 1) * D_MODEL))[t];
    xv.x += g0 * w20.x + g1 * w21.x;
    xv.y += g0 * w20.y + g1 * w21.y;
    xv.z += g0 * w20.z + g1 * w21.z;
    xv.w += g0 * w20.w + g1 * w21.w;
    ((float4*)xbuf)[(size_t)tok * D4 + t] = xv;
    float ss2 = xv.x * xv.x + xv.y * xv.y + xv.z * xv.z + xv.w * xv.w;
    ss2 = block_reduce_sum(ss2, sred);
    if (t == 0) rstd[tok] = rsqrtf(ss2 * (1.0f / D_MODEL) + EPSF);
}

// ---- final rmsnorm + factorized tied-projection logits -----------------------
// logits[t, v1*160+v2] = sum_i c1[v1,i] * T[v2,i],  T[v2,i] = sum_j Xn[i,j]*c2[v2,j]
// 512 threads/block; phase C: ONE 8x8 output tile per thread (500 active).
// REGISTER BUDGET: __launch_bounds__'s 2nd arg is a MIN waves/EU (occupancy
// floor) -- round-3 counters showed the backend then targets 8 waves/EU and
// caps VGPRs at 64, scratch-spilling the 64 accumulators (13.9 GB phantom HBM
// traffic, VGPR_Count=64). amdgpu_waves_per_eu(2,4) clamps occupancy from
// ABOVE: max 4 waves/EU -> up to 128 VGPRs, so the ~92-reg live set
// (64 acc + 16 Bc + 4 Ar + addressing) stays in registers. Bc is staged in
// halves of 4 to keep peak pressure under the budget.
// c1 (25.6 KB) is read directly (L1-resident, 20-lane broadcast) -- not LDS.
// Phase C lane mapping: tv2 varies FASTEST across lanes -> a wave's stores
// cover contiguous output rows (coalesced full-line writes, no RMW fetch).
// sT is xor-swizzled by (v2>>3) so tv2-spread lanes hit distinct bank groups.
__global__ __launch_bounds__(512) __attribute__((amdgpu_waves_per_eu(2, 4)))
void logits_kernel(
        const float* __restrict__ xbuf,
        const float* __restrict__ rstd,
        const float* __restrict__ fnw,
        const float* __restrict__ c1,
        const float* __restrict__ c2,
        float* __restrict__ out) {
    __shared__ float sX[1024];    // swizzled float4 rows: slot i*8 + (j4 ^ (i&7))
    __shared__ float sT[5120];    // swizzled: slot v2*8 + (i4 ^ ((v2>>3)&7))
    int tok = blockIdx.x, t = threadIdx.x;

    // phase A: final rmsnorm into LDS (first 256 threads; one float4 each)
    if (t < 256) {
        float rs = rstd[tok];
        float4 xv = ((const float4*)xbuf)[(size_t)tok * D4 + t];
        float4 fn = ((const float4*)fnw)[t];
        float4 xs;
        xs.x = xv.x * rs * fn.x; xs.y = xv.y * rs * fn.y;
        xs.z = xv.z * rs * fn.z; xs.w = xv.w * rs * fn.w;
        int i = t >> 3, j4 = t & 7;
        ((float4*)sX)[i * 8 + (j4 ^ (i & 7))] = xs;
    }
    __syncthreads();

    // phase B: T[v2][i]; each thread owns one i-row (in regs) x 10 v2
    {
        int i = t & 31;
        int vg = t >> 5;  // 0..15
        float4 xr[8];
        #pragma unroll
        for (int j4 = 0; j4 < 8; ++j4)
            xr[j4] = ((const float4*)sX)[i * 8 + (j4 ^ (i & 7))];
        #pragma unroll
        for (int o = 0; o < 10; ++o) {
            int v2 = vg * 10 + o;
            const float4* c2p = (const float4*)(c2 + v2 * 32);
            float acc = 0.0f;
            #pragma unroll
            for (int j4 = 0; j4 < 8; ++j4) {
                float4 cb = c2p[j4];
                acc += cb.x * xr[j4].x + cb.y * xr[j4].y +
                       cb.z * xr[j4].z + cb.w * xr[j4].w;
            }
            int swzB = (v2 >> 3) & 7;
            sT[(v2 * 8 + ((i >> 2) ^ swzB)) * 4 + (i & 3)] = acc;
        }
    }
    __syncthreads();

    // phase C: one 8x8 register tile per thread over the 200x160 output,
    // tv2 lane-fastest for coalesced stores
    if (t < 500) {
        int tv2 = t % 20, tv1 = t / 20;  // lanes vary tv2 fastest
        int v1b = tv1 * 8, v2b = tv2 * 8;
        int swzB = tv2 & 7;
        float acc[8][8];
        #pragma unroll
        for (int r = 0; r < 8; ++r)
            #pragma unroll
            for (int cc = 0; cc < 8; ++cc) acc[r][cc] = 0.0f;
        const float4* c1p = (const float4*)c1;  // c1[v1] = 8 float4s
        #pragma unroll
        for (int i4 = 0; i4 < 8; ++i4) {
            #pragma unroll
            for (int hh = 0; hh < 2; ++hh) {      // Bc in halves of 4: peak live regs ~92
                float4 Bc[4];
                #pragma unroll
                for (int cc = 0; cc < 4; ++cc)
                    Bc[cc] = ((const float4*)sT)[(v2b + hh * 4 + cc) * 8 + (i4 ^ swzB)];
                #pragma unroll
                for (int r = 0; r < 8; ++r) {
                    float4 Ar = c1p[(v1b + r) * 8 + i4];   // L1-hit broadcast load
                    #pragma unroll
                    for (int cc = 0; cc < 4; ++cc)
                        acc[r][hh * 4 + cc] += Ar.x * Bc[cc].x + Ar.y * Bc[cc].y +
                                               Ar.z * Bc[cc].z + Ar.w * Bc[cc].w;
                }
            }
        }
        size_t obase = (size_t)tok * 32000;
        #pragma unroll
        for (int r = 0; r < 8; ++r) {
            float4 o0 = {acc[r][0], acc[r][1], acc[r][2], acc[r][3]};
            float4 o1 = {acc[r][4], acc[r][5], acc[r][6], acc[r][7]};
            float* op = out + obase + (size_t)(v1b + r) * 160 + v2b;
            *(float4*)op = o0;
            *(float4*)(op + 4) = o1;
        }
    }
}

extern "C" void kernel_launch(void* const* d_in, const int* in_sizes, int n_in,
                              void* d_out, int out_size, void* d_ws, size_t ws_size,
                              hipStream_t stream) {
    const int*   ids = (const int*)d_in[0];
    const float* c1  = (const float*)d_in[1];
    const float* c2  = (const float*)d_in[2];
    const float* lam = (const float*)d_in[3];
    const float* u   = (const float*)d_in[4];
    const float* v   = (const float*)d_in[5];
    const float* w1  = (const float*)d_in[6];
    const float* w2  = (const float*)d_in[7];
    const float* n1w = (const float*)d_in[8];
    const float* n2w = (const float*)d_in[9];
    const float* fnw = (const float*)d_in[10];
    float* out = (float*)d_out;

    float* ws     = (float*)d_ws;
    float* xbuf   = ws;                                   // 4096*1024
    float* rstd   = xbuf + (size_t)NTOK * D_MODEL;        // 4096
    float* decay  = rstd + NTOK;                          // 8192
    float* apow   = decay + NLAYER * D_MODEL;             // 8192
    float* carry  = apow + NLAYER * D_MODEL;              // 2*64*1024
    float* hstart = carry + (size_t)BATCH * NCH * D_MODEL;// 2*64*1024

    precompute_kernel<<<32, 256, 0, stream>>>(lam, decay, apow);
    embed_kernel<<<NTOK, 256, 0, stream>>>(ids, c1, c2, xbuf, rstd);
    for (int l = 0; l < NLAYER; ++l) {
        scan1_kernel<<<BATCH * NCH * 4, 256, 0, stream>>>(xbuf, rstd, decay, v, n1w, carry, l);
        scan2_kernel<<<BATCH * D_MODEL / 256, 256, 0, stream>>>(carry, apow, hstart, l);
        scan3_kernel<<<BATCH * NCH * 4, 256, 0, stream>>>(xbuf, rstd, hstart, decay, v, u, n1w, l);
        ffn_kernel<<<NTOK, 256, 0, stream>>>(xbuf, rstd, n2w, w1, w2, l);
    }
    logits_kernel<<<NTOK, 512, 0, stream>>>(xbuf, rstd, fnw, c1, c2, out);
}